// Round 5
// baseline (150.067 us; speedup 1.0000x reference)
//
#include <hip/hip_runtime.h>
#include <hip/hip_bf16.h>
#include <math.h>

typedef __attribute__((ext_vector_type(8))) short short8;
typedef __attribute__((ext_vector_type(16))) float f32x16;

#define NB 4096
#define DIM 128
#define NJ 32                  // j-splits: each block handles NB/NJ = 128 j's
#define JTILES (NB / NJ / 32)  // 4 j-tiles of 32 per block
// EXP_SCALE = (1/TAU) * log2(e) = 20 * 1.4426950408889634  (folded into Y operand)
#define EXP_SCALE 28.853900817779268f

__device__ inline unsigned short f2bf(float f) {
  unsigned int u = __builtin_bit_cast(unsigned int, f);
  u += 0x7FFFu + ((u >> 16) & 1u);
  return (unsigned short)(u >> 16);
}

__device__ inline float wave_sum(float v) {
#pragma unroll
  for (int off = 32; off >= 1; off >>= 1) v += __shfl_xor(v, off, 64);
  return v;
}

// Detect int64-vs-int32 links (int64 hi-words of values <2^31 are all zero;
// impossible for 128 consecutive real int32 links) + zero the output scalar.
__global__ __launch_bounds__(64) void k_init(const int* links32, int* flag, float* out) {
  if (threadIdx.x == 0) {
    int all0 = 1;
    for (int w = 1; w < 256; w += 2) all0 &= (links32[w] == 0);
    *flag = all0;
    out[0] = 0.0f;
  }
}

// Gather + L2-normalize the 8192 referenced rows.
// Outputs: f32 rows (exact diag dot) + bf16 K-chunked layouts Zc[16][4096][8]:
//   unscaled (X role / arg1) and pre-scaled by EXP_SCALE (Y role / arg0).
__global__ __launch_bounds__(256) void k_normalize(
    const float* __restrict__ emb, const int* __restrict__ links,
    const int* __restrict__ flag,
    float* __restrict__ Zi_f, float* __restrict__ Zj_f,
    unsigned short* __restrict__ Zic, unsigned short* __restrict__ Zjc,
    unsigned short* __restrict__ Zis, unsigned short* __restrict__ Zjs) {
  int wid = threadIdx.x >> 6, lane = threadIdx.x & 63;
  int r = blockIdx.x * 4 + wid;   // 0..8191
  int side = r >> 12;             // 0 => zis (links[:,0]), 1 => zjs (links[:,1])
  int p = r & (NB - 1);
  int q = 2 * p + side;
  int idx = (*flag) ? links[2 * q] : links[q];  // int64 mode: lo word
  const float* src = emb + (long long)idx * DIM;
  float x0 = src[lane], x1 = src[lane + 64];
  float ss = wave_sum(x0 * x0 + x1 * x1);
  float inv = 1.0f / fmaxf(sqrtf(ss), 1e-12f);
  x0 *= inv; x1 *= inv;
  float* Zf = side ? Zj_f : Zi_f;
  unsigned short* Zc = side ? Zjc : Zic;
  unsigned short* Zs = side ? Zjs : Zis;
  Zf[p * DIM + lane] = x0;
  Zf[p * DIM + 64 + lane] = x1;
  size_t o0 = (((lane >> 3) + 0) * NB + p) * 8 + (lane & 7);
  size_t o1 = (((lane >> 3) + 8) * NB + p) * 8 + (lane & 7);
  Zc[o0] = f2bf(x0);
  Zc[o1] = f2bf(x1);
  Zs[o0] = f2bf(x0 * EXP_SCALE);
  Zs[o1] = f2bf(x1 * EXP_SCALE);
}

// diag[i] = (zis_i . zjs_i) / TAU, in f32 (the softmax numerator logit)
__global__ __launch_bounds__(256) void k_diag(
    const float* __restrict__ Zi_f, const float* __restrict__ Zj_f,
    float* __restrict__ diag) {
  int wid = threadIdx.x >> 6, lane = threadIdx.x & 63;
  int i = blockIdx.x * 4 + wid;
  float a0 = Zi_f[i * DIM + lane], a1 = Zi_f[i * DIM + 64 + lane];
  float b0 = Zj_f[i * DIM + lane], b1 = Zj_f[i * DIM + 64 + lane];
  float s = wave_sum(a0 * b0 + a1 * b1);
  if (lane == 0) diag[i] = s * 20.0f;
}

// One pass: rows i of L = X.Y^T/tau, accumulate sum_j exp(L[i][j]) (Y carries
// the 1/(tau*ln2) scale; the -max shift is absorbed in k_final's log).
// Layout-agnostic via dual per-reg probe MFMAs. Software-pipelined j-loop:
// next tile's Y loads issue before current tile's MFMA chain + exp epilogue.
// z: 0=AB(X=Zic,Y=Zjs) 1=AA(skip) 2=BA(X=Zjc,Y=Zis) 3=BB(skip)
__global__ __launch_bounds__(256) void k_pass(
    const unsigned short* __restrict__ Zic, const unsigned short* __restrict__ Zjc,
    const unsigned short* __restrict__ Zis, const unsigned short* __restrict__ Zjs,
    float* __restrict__ rpart) {
  int z = blockIdx.z;
  const unsigned short* Xc = (z <= 1) ? Zic : Zjc;
  const unsigned short* Yc = (z == 1 || z == 2) ? Zis : Zjs;
  const bool skip = (z & 1);

  __shared__ float buf[256];
  int tid = threadIdx.x;
  int wid = tid >> 6, lane = tid & 63;
  buf[tid] = 0.0f;
  __syncthreads();

  int i0 = blockIdx.x * 256 + wid * 64;  // wave owns 64 loss-rows (2 col-tiles)
  int jb = blockIdx.y * (NB / NJ);       // 128 j's = 4 tiles of 32
  int lr = lane & 31;
  int hi = lane >> 5;                    // k-half selector within fragment

  // --- dual per-reg layout probe (verified R3/R4) ---
  short8 pj, pc;
  unsigned short blr = f2bf((float)lr);
#pragma unroll
  for (int e = 0; e < 8; ++e) { pj[e] = (short)blr; pc[e] = (short)0x3D80; }
  f32x16 pr = {}, pn = {};
  pr = __builtin_amdgcn_mfma_f32_32x32x16_bf16(pj, pc, pr, 0, 0, 0);
  pn = __builtin_amdgcn_mfma_f32_32x32x16_bf16(pc, pj, pn, 0, 0, 0);
  // pack: high byte = imap (store target), low byte = imap - jmap + 64 (diag key)
  int pk[16];
#pragma unroll
  for (int r = 0; r < 16; ++r) {
    int jm = (int)(pr[r] + 0.5f), im = (int)(pn[r] + 0.5f);
    pk[r] = (im << 8) | (im - jm + 64);
  }

  // Hoist X fragments for the whole j loop: 8 contiguous bf16 = 16B load
  short8 xf[2][8];
#pragma unroll
  for (int t = 0; t < 2; ++t)
#pragma unroll
    for (int ks = 0; ks < 8; ++ks)
      xf[t][ks] = *reinterpret_cast<const short8*>(
          Xc + ((size_t)(ks * 2 + hi) * NB + (i0 + t * 32 + lr)) * 8);

  float rs0[16], rs1[16];
#pragma unroll
  for (int r = 0; r < 16; ++r) { rs0[r] = 0.0f; rs1[r] = 0.0f; }

  // prologue: load tile 0
  short8 yf[2][8];
#pragma unroll
  for (int ks = 0; ks < 8; ++ks)
    yf[0][ks] = *reinterpret_cast<const short8*>(
        Yc + ((size_t)(ks * 2 + hi) * NB + (jb + lr)) * 8);

#pragma unroll
  for (int jt = 0; jt < JTILES; ++jt) {
    int cur = jt & 1, nxt = cur ^ 1;
    int j0 = jb + jt * 32;
    if (jt + 1 < JTILES) {  // issue next tile's loads FIRST (latency overlap)
      int j0n = j0 + 32;
#pragma unroll
      for (int ks = 0; ks < 8; ++ks)
        yf[nxt][ks] = *reinterpret_cast<const short8*>(
            Yc + ((size_t)(ks * 2 + hi) * NB + (j0n + lr)) * 8);
    }
    f32x16 acc0 = {}, acc1 = {};
#pragma unroll
    for (int ks = 0; ks < 8; ++ks) {
      acc0 = __builtin_amdgcn_mfma_f32_32x32x16_bf16(yf[cur][ks], xf[0][ks], acc0, 0, 0, 0);
      acc1 = __builtin_amdgcn_mfma_f32_32x32x16_bf16(yf[cur][ks], xf[1][ks], acc1, 0, 0, 0);
    }
    // diag can only hit a tile whose j-range intersects the wave's i-range
    int t0 = j0 - i0 + 64, t1 = t0 - 32;  // compare keys
    bool chk0 = skip && ((unsigned)(t0 - 33) <= 62u);
    bool chk1 = skip && ((unsigned)(t1 - 33) <= 62u);
#pragma unroll
    for (int r = 0; r < 16; ++r) {
      float e0 = exp2f(acc0[r]);
      float e1 = exp2f(acc1[r]);
      if (chk0 && ((pk[r] & 0xFF) == t0)) e0 = 0.0f;
      if (chk1 && ((pk[r] & 0xFF) == t1)) e1 = 0.0f;
      rs0[r] += e0;
      rs1[r] += e1;
    }
  }
  // LDS reduce (2 lanes x 16 regs share each output column)
  int base = wid * 64;
#pragma unroll
  for (int r = 0; r < 16; ++r) {
    int im = pk[r] >> 8;
    atomicAdd(&buf[base + im], rs0[r]);
    atomicAdd(&buf[base + 32 + im], rs1[r]);
  }
  __syncthreads();
  rpart[((size_t)(z * NJ + blockIdx.y)) * NB + blockIdx.x * 256 + tid] = buf[tid];
}

__global__ __launch_bounds__(256) void k_final(
    const float* __restrict__ rpart, const float* __restrict__ diag,
    float* __restrict__ out) {
  int i = blockIdx.x * 256 + threadIdx.x;
  float sa = 0.0f, sb = 0.0f;
#pragma unroll
  for (int y = 0; y < NJ; ++y) {
    sa += rpart[(size_t)(0 * NJ + y) * NB + i] + rpart[(size_t)(1 * NJ + y) * NB + i];
    sb += rpart[(size_t)(2 * NJ + y) * NB + i] + rpart[(size_t)(3 * NJ + y) * NB + i];
  }
  // raw sums carry e^{+20}: lse = 20 + ln(sum * e^-20) = ln(sum)
  float v = 0.5f * (logf(sa) + logf(sb)) - diag[i];
  v = wave_sum(v);
  __shared__ float sred[4];
  if ((threadIdx.x & 63) == 0) sred[threadIdx.x >> 6] = v;
  __syncthreads();
  if (threadIdx.x == 0)
    atomicAdd(out, (sred[0] + sred[1] + sred[2] + sred[3]) * (1.0f / NB));
}

extern "C" void kernel_launch(void* const* d_in, const int* in_sizes, int n_in,
                              void* d_out, int out_size, void* d_ws, size_t ws_size,
                              hipStream_t stream) {
  const float* emb = (const float*)d_in[0];
  const int* links = (const int*)d_in[1];
  char* ws = (char*)d_ws;
  float* Zi_f = (float*)(ws + 0);                        // 2 MB (dead after k_diag)
  float* Zj_f = (float*)(ws + 2097152);                  // 2 MB
  unsigned short* Zic = (unsigned short*)(ws + 4194304); // 1 MB
  unsigned short* Zjc = (unsigned short*)(ws + 5242880); // 1 MB
  unsigned short* Zis = (unsigned short*)(ws + 6291456); // 1 MB (scaled)
  unsigned short* Zjs = (unsigned short*)(ws + 7340032); // 1 MB (scaled)
  float* diag = (float*)(ws + 8388608);                  // 16 KB
  int* flag = (int*)(ws + 8404992);                      // 4 B
  float* rpart = (float*)(ws + 0);                       // 2 MB, overlays Zi_f
  float* out = (float*)d_out;

  hipLaunchKernelGGL(k_init, dim3(1), dim3(64), 0, stream, links, flag, out);
  hipLaunchKernelGGL(k_normalize, dim3(2048), dim3(256), 0, stream,
                     emb, links, flag, Zi_f, Zj_f, Zic, Zjc, Zis, Zjs);
  hipLaunchKernelGGL(k_diag, dim3(1024), dim3(256), 0, stream, Zi_f, Zj_f, diag);
  hipLaunchKernelGGL(k_pass, dim3(16, NJ, 4), dim3(256), 0, stream,
                     Zic, Zjc, Zis, Zjs, rpart);
  hipLaunchKernelGGL(k_final, dim3(16), dim3(256), 0, stream,
                     rpart, diag, out);
}

// Round 6
// 115.621 us; speedup vs baseline: 1.2979x; 1.2979x over previous
//
#include <hip/hip_runtime.h>
#include <hip/hip_bf16.h>
#include <math.h>

typedef __attribute__((ext_vector_type(8))) short short8;
typedef __attribute__((ext_vector_type(16))) float f32x16;

#define NB 4096
#define DIM 128
#define NJ 16                  // j-splits: each block handles NB/NJ = 256 j's
#define JTILES (NB / NJ / 32)  // 8 j-tiles of 32 per block
// EXP_SCALE = (1/TAU) * log2(e) = 20 * 1.4426950408889634
#define EXP_SCALE 28.853900817779268f

__device__ inline unsigned short f2bf(float f) {
  unsigned int u = __builtin_bit_cast(unsigned int, f);
  u += 0x7FFFu + ((u >> 16) & 1u);
  return (unsigned short)(u >> 16);
}

__device__ inline float wave_sum(float v) {
#pragma unroll
  for (int off = 32; off >= 1; off >>= 1) v += __shfl_xor(v, off, 64);
  return v;
}

// Detect int64-vs-int32 links (int64 hi-words of values <2^31 are all zero;
// impossible for 128 consecutive real int32 links) + zero the output scalar.
__global__ __launch_bounds__(64) void k_init(const int* links32, int* flag, float* out) {
  if (threadIdx.x == 0) {
    int all0 = 1;
    for (int w = 1; w < 256; w += 2) all0 &= (links32[w] == 0);
    *flag = all0;
    out[0] = 0.0f;
  }
}

// Gather + L2-normalize the 8192 referenced rows.
// Outputs: f32 rows (for exact diag dot) + bf16 K-chunked layout Zc[16][4096][8]
__global__ __launch_bounds__(256) void k_normalize(
    const float* __restrict__ emb, const int* __restrict__ links,
    const int* __restrict__ flag,
    float* __restrict__ Zi_f, float* __restrict__ Zj_f,
    unsigned short* __restrict__ Zic, unsigned short* __restrict__ Zjc) {
  int wid = threadIdx.x >> 6, lane = threadIdx.x & 63;
  int r = blockIdx.x * 4 + wid;   // 0..8191
  int side = r >> 12;             // 0 => zis (links[:,0]), 1 => zjs (links[:,1])
  int p = r & (NB - 1);
  int q = 2 * p + side;
  int idx = (*flag) ? links[2 * q] : links[q];  // int64 mode: lo word
  const float* src = emb + (long long)idx * DIM;
  float x0 = src[lane], x1 = src[lane + 64];
  float ss = wave_sum(x0 * x0 + x1 * x1);
  float inv = 1.0f / fmaxf(sqrtf(ss), 1e-12f);
  x0 *= inv; x1 *= inv;
  float* Zf = side ? Zj_f : Zi_f;
  unsigned short* Zc = side ? Zjc : Zic;
  Zf[p * DIM + lane] = x0;
  Zf[p * DIM + 64 + lane] = x1;
  Zc[(((lane >> 3) + 0) * NB + p) * 8 + (lane & 7)] = f2bf(x0);
  Zc[(((lane >> 3) + 8) * NB + p) * 8 + (lane & 7)] = f2bf(x1);
}

// diag[i] = (zis_i . zjs_i) / TAU, in f32 (the softmax numerator logit)
__global__ __launch_bounds__(256) void k_diag(
    const float* __restrict__ Zi_f, const float* __restrict__ Zj_f,
    float* __restrict__ diag) {
  int wid = threadIdx.x >> 6, lane = threadIdx.x & 63;
  int i = blockIdx.x * 4 + wid;
  float a0 = Zi_f[i * DIM + lane], a1 = Zi_f[i * DIM + 64 + lane];
  float b0 = Zj_f[i * DIM + lane], b1 = Zj_f[i * DIM + 64 + lane];
  float s = wave_sum(a0 * b0 + a1 * b1);
  if (lane == 0) diag[i] = s * 20.0f;
}

// One pass: rows i of L = X.Y^T/tau, accumulate sum_j exp(L[i][j]-20),
// skipping j==i on AA/BB. Layout-agnostic via dual per-reg probe MFMAs.
// Y tiles staged through LDS (T3-min 2-phase + T14 split): loads for tile
// t+1 issue before tile t's MFMAs; ds_write lands after them; one barrier
// per tile. VMEM ops per tile per thread: 2 (vs 8 direct) — shared by 4 waves.
// z: 0=AB(X=Zic,Y=Zjc) 1=AA(skip) 2=BA(X=Zjc,Y=Zic) 3=BB(skip)
__global__ __launch_bounds__(256) void k_pass(
    const unsigned short* __restrict__ Zic, const unsigned short* __restrict__ Zjc,
    float* __restrict__ rpart) {
  int z = blockIdx.z;
  const unsigned short* Xc = (z <= 1) ? Zic : Zjc;
  const unsigned short* Yc = (z == 1 || z == 2) ? Zic : Zjc;
  const bool skip = (z & 1);

  __shared__ float buf[256];
  __shared__ unsigned short ytile[2][4096];  // [dbuf][chunk16][row32][8] = 8 KB each

  int tid = threadIdx.x;
  int wid = tid >> 6, lane = tid & 63;
  buf[tid] = 0.0f;

  int i0 = blockIdx.x * 256 + wid * 64;  // wave owns 64 loss-rows (2 col-tiles)
  int jb = blockIdx.y * (NB / NJ);       // 256 j's = 8 tiles of 32
  int lr = lane & 31;
  int hi = lane >> 5;                    // k-half selector within fragment

  // staging geometry: piece p = wid*128 + q*64 + lane covers chunk p>>5, row p&31
  int p0 = wid * 128 + lane;             // q=0 piece; q=1 is p0+64
  int c0 = p0 >> 5, r0 = p0 & 31;
  int c1 = (p0 + 64) >> 5, r1 = (p0 + 64) & 31;

  // --- dual per-reg layout probe (verified R3-R5) ---
  short8 pj, pc;
  unsigned short blr = f2bf((float)lr);
#pragma unroll
  for (int e = 0; e < 8; ++e) { pj[e] = (short)blr; pc[e] = (short)0x3D80; }
  f32x16 pr = {}, pn = {};
  pr = __builtin_amdgcn_mfma_f32_32x32x16_bf16(pj, pc, pr, 0, 0, 0);
  pn = __builtin_amdgcn_mfma_f32_32x32x16_bf16(pc, pj, pn, 0, 0, 0);
  // pack: high byte = imap (store target), low byte = imap - jmap + 64 (diag key)
  int pk[16];
#pragma unroll
  for (int r = 0; r < 16; ++r) {
    int jm = (int)(pr[r] + 0.5f), im = (int)(pn[r] + 0.5f);
    pk[r] = (im << 8) | (im - jm + 64);
  }

  // Hoist X fragments for the whole j loop: 8 contiguous bf16 = 16B load
  short8 xf[2][8];
#pragma unroll
  for (int t = 0; t < 2; ++t)
#pragma unroll
    for (int ks = 0; ks < 8; ++ks)
      xf[t][ks] = *reinterpret_cast<const short8*>(
          Xc + ((size_t)(ks * 2 + hi) * NB + (i0 + t * 32 + lr)) * 8);

  float rs0[16], rs1[16];
#pragma unroll
  for (int r = 0; r < 16; ++r) { rs0[r] = 0.0f; rs1[r] = 0.0f; }

  // prologue: stage tile 0 into buffer 0
  short8 stg0, stg1;
  stg0 = *reinterpret_cast<const short8*>(Yc + ((size_t)c0 * NB + jb + r0) * 8);
  stg1 = *reinterpret_cast<const short8*>(Yc + ((size_t)c1 * NB + jb + r1) * 8);
  *reinterpret_cast<short8*>(&ytile[0][(size_t)p0 * 8]) = stg0;
  *reinterpret_cast<short8*>(&ytile[0][(size_t)(p0 + 64) * 8]) = stg1;
  __syncthreads();

  for (int jt = 0; jt < JTILES; ++jt) {
    int cur = jt & 1, nxt = cur ^ 1;
    int j0 = jb + jt * 32;
    if (jt + 1 < JTILES) {  // issue next tile's loads EARLY (latency overlap)
      int j0n = j0 + 32;
      stg0 = *reinterpret_cast<const short8*>(Yc + ((size_t)c0 * NB + j0n + r0) * 8);
      stg1 = *reinterpret_cast<const short8*>(Yc + ((size_t)c1 * NB + j0n + r1) * 8);
    }
    // compute current tile from LDS
    f32x16 acc0 = {}, acc1 = {};
#pragma unroll
    for (int ks = 0; ks < 8; ++ks) {
      short8 yfr = *reinterpret_cast<const short8*>(
          &ytile[cur][(size_t)(((ks * 2 + hi) * 32) + lr) * 8]);
      acc0 = __builtin_amdgcn_mfma_f32_32x32x16_bf16(yfr, xf[0][ks], acc0, 0, 0, 0);
      acc1 = __builtin_amdgcn_mfma_f32_32x32x16_bf16(yfr, xf[1][ks], acc1, 0, 0, 0);
    }
    if (jt + 1 < JTILES) {  // write-late: vmcnt drain hidden under MFMAs
      *reinterpret_cast<short8*>(&ytile[nxt][(size_t)p0 * 8]) = stg0;
      *reinterpret_cast<short8*>(&ytile[nxt][(size_t)(p0 + 64) * 8]) = stg1;
    }
    // epilogue: exp + diag skip (overlaps ds_write completion)
    int t0 = j0 - i0 + 64, t1 = t0 - 32;  // compare keys
    bool chk0 = skip && ((unsigned)(t0 - 33) <= 62u);
    bool chk1 = skip && ((unsigned)(t1 - 33) <= 62u);
#pragma unroll
    for (int r = 0; r < 16; ++r) {
      float e0 = exp2f(fmaf(acc0[r], EXP_SCALE, -EXP_SCALE));
      float e1 = exp2f(fmaf(acc1[r], EXP_SCALE, -EXP_SCALE));
      if (chk0 && ((pk[r] & 0xFF) == t0)) e0 = 0.0f;
      if (chk1 && ((pk[r] & 0xFF) == t1)) e1 = 0.0f;
      rs0[r] += e0;
      rs1[r] += e1;
    }
    __syncthreads();
  }
  // LDS reduce (2 lanes x 16 regs share each output column)
  int base = wid * 64;
#pragma unroll
  for (int r = 0; r < 16; ++r) {
    int im = pk[r] >> 8;
    atomicAdd(&buf[base + im], rs0[r]);
    atomicAdd(&buf[base + 32 + im], rs1[r]);
  }
  __syncthreads();
  rpart[((size_t)(z * NJ + blockIdx.y)) * NB + blockIdx.x * 256 + tid] = buf[tid];
}

__global__ __launch_bounds__(256) void k_final(
    const float* __restrict__ rpart, const float* __restrict__ diag,
    float* __restrict__ out) {
  int i = blockIdx.x * 256 + threadIdx.x;
  float sa = 0.0f, sb = 0.0f;
#pragma unroll
  for (int y = 0; y < NJ; ++y) {
    sa += rpart[(size_t)(0 * NJ + y) * NB + i] + rpart[(size_t)(1 * NJ + y) * NB + i];
    sb += rpart[(size_t)(2 * NJ + y) * NB + i] + rpart[(size_t)(3 * NJ + y) * NB + i];
  }
  // 0.5*(lse_a + lse_b) - diag ; lse = 20 + ln(sum)
  float v = 0.5f * (40.0f + logf(sa) + logf(sb)) - diag[i];
  v = wave_sum(v);
  __shared__ float sred[4];
  if ((threadIdx.x & 63) == 0) sred[threadIdx.x >> 6] = v;
  __syncthreads();
  if (threadIdx.x == 0)
    atomicAdd(out, (sred[0] + sred[1] + sred[2] + sred[3]) * (1.0f / NB));
}

extern "C" void kernel_launch(void* const* d_in, const int* in_sizes, int n_in,
                              void* d_out, int out_size, void* d_ws, size_t ws_size,
                              hipStream_t stream) {
  const float* emb = (const float*)d_in[0];
  const int* links = (const int*)d_in[1];
  char* ws = (char*)d_ws;
  float* Zi_f = (float*)(ws + 0);                        // 2 MB (dead after k_diag)
  float* Zj_f = (float*)(ws + 2097152);                  // 2 MB
  unsigned short* Zic = (unsigned short*)(ws + 4194304); // 1 MB
  unsigned short* Zjc = (unsigned short*)(ws + 5242880); // 1 MB
  float* rpart = (float*)(ws + 6291456);                 // 4*NJ*NB*4 = 1 MB
  float* diag = (float*)(ws + 7340032);                  // 16 KB
  int* flag = (int*)(ws + 7356416);                      // 4 B
  float* out = (float*)d_out;

  hipLaunchKernelGGL(k_init, dim3(1), dim3(64), 0, stream, links, flag, out);
  hipLaunchKernelGGL(k_normalize, dim3(2048), dim3(256), 0, stream,
                     emb, links, flag, Zi_f, Zj_f, Zic, Zjc);
  hipLaunchKernelGGL(k_diag, dim3(1024), dim3(256), 0, stream, Zi_f, Zj_f, diag);
  hipLaunchKernelGGL(k_pass, dim3(16, NJ, 4), dim3(256), 0, stream,
                     Zic, Zjc, rpart);
  hipLaunchKernelGGL(k_final, dim3(16), dim3(256), 0, stream,
                     rpart, diag, out);
}

// Round 7
// 105.209 us; speedup vs baseline: 1.4264x; 1.0990x over previous
//
#include <hip/hip_runtime.h>
#include <hip/hip_bf16.h>
#include <math.h>

typedef __attribute__((ext_vector_type(8))) short short8;
typedef __attribute__((ext_vector_type(16))) float f32x16;

#define NB 4096
#define DIM 128
#define NJ 16                  // j-splits: each block handles NB/NJ = 256 j's
#define JTILES (NB / NJ / 32)  // 8 j-tiles of 32 per block
// EXP_SCALE = (1/TAU) * log2(e) = 20 * 1.4426950408889634
#define EXP_SCALE 28.853900817779268f

__device__ inline unsigned short f2bf(float f) {
  unsigned int u = __builtin_bit_cast(unsigned int, f);
  u += 0x7FFFu + ((u >> 16) & 1u);
  return (unsigned short)(u >> 16);
}

__device__ inline float wave_sum(float v) {
#pragma unroll
  for (int off = 32; off >= 1; off >>= 1) v += __shfl_xor(v, off, 64);
  return v;
}

// Detect int64-vs-int32 links (int64 hi-words of values <2^31 are all zero;
// impossible for 128 consecutive real int32 links) + zero the output scalar.
__global__ __launch_bounds__(64) void k_init(const int* links32, int* flag, float* out) {
  if (threadIdx.x == 0) {
    int all0 = 1;
    for (int w = 1; w < 256; w += 2) all0 &= (links32[w] == 0);
    *flag = all0;
    out[0] = 0.0f;
  }
}

// Gather + L2-normalize the 8192 referenced rows.
// Outputs: f32 rows (for exact diag dot) + bf16 K-chunked layout Zc[16][4096][8]
__global__ __launch_bounds__(256) void k_normalize(
    const float* __restrict__ emb, const int* __restrict__ links,
    const int* __restrict__ flag,
    float* __restrict__ Zi_f, float* __restrict__ Zj_f,
    unsigned short* __restrict__ Zic, unsigned short* __restrict__ Zjc) {
  int wid = threadIdx.x >> 6, lane = threadIdx.x & 63;
  int r = blockIdx.x * 4 + wid;   // 0..8191
  int side = r >> 12;             // 0 => zis (links[:,0]), 1 => zjs (links[:,1])
  int p = r & (NB - 1);
  int q = 2 * p + side;
  int idx = (*flag) ? links[2 * q] : links[q];  // int64 mode: lo word
  const float* src = emb + (long long)idx * DIM;
  float x0 = src[lane], x1 = src[lane + 64];
  float ss = wave_sum(x0 * x0 + x1 * x1);
  float inv = 1.0f / fmaxf(sqrtf(ss), 1e-12f);
  x0 *= inv; x1 *= inv;
  float* Zf = side ? Zj_f : Zi_f;
  unsigned short* Zc = side ? Zjc : Zic;
  Zf[p * DIM + lane] = x0;
  Zf[p * DIM + 64 + lane] = x1;
  Zc[(((lane >> 3) + 0) * NB + p) * 8 + (lane & 7)] = f2bf(x0);
  Zc[(((lane >> 3) + 8) * NB + p) * 8 + (lane & 7)] = f2bf(x1);
}

// diag[i] = (zis_i . zjs_i) / TAU, in f32 (the softmax numerator logit)
__global__ __launch_bounds__(256) void k_diag(
    const float* __restrict__ Zi_f, const float* __restrict__ Zj_f,
    float* __restrict__ diag) {
  int wid = threadIdx.x >> 6, lane = threadIdx.x & 63;
  int i = blockIdx.x * 4 + wid;
  float a0 = Zi_f[i * DIM + lane], a1 = Zi_f[i * DIM + 64 + lane];
  float b0 = Zj_f[i * DIM + lane], b1 = Zj_f[i * DIM + 64 + lane];
  float s = wave_sum(a0 * b0 + a1 * b1);
  if (lane == 0) diag[i] = s * 20.0f;
}

// One pass: rows i of L = X.Y^T/tau, accumulate sum_j exp(L[i][j]-20),
// skipping j==i on AA/BB. Layout-agnostic via dual per-reg probe MFMAs,
// compressed to 5 regs (1-bit diag mask + packed imap). Wave owns ONE
// 32x32 acc tile (low VGPR, no spill); no LDS staging, no in-loop barriers;
// latency hidden by occupancy (2048 blocks, ~4 waves/SIMD).
// z: 0=AB(X=Zic,Y=Zjc) 1=AA(skip) 2=BA(X=Zjc,Y=Zic) 3=BB(skip)
__global__ __launch_bounds__(256) void k_pass(
    const unsigned short* __restrict__ Zic, const unsigned short* __restrict__ Zjc,
    float* __restrict__ rpart) {
  int z = blockIdx.z;
  const unsigned short* Xc = (z <= 1) ? Zic : Zjc;
  const unsigned short* Yc = (z == 1 || z == 2) ? Zic : Zjc;
  const bool skip = (z & 1);

  __shared__ float buf[128];
  int tid = threadIdx.x;
  int wid = tid >> 6, lane = tid & 63;
  if (tid < 128) buf[tid] = 0.0f;
  __syncthreads();

  int it0 = blockIdx.x * 128 + wid * 32;  // wave's 32 loss-rows (one tile)
  int jb = blockIdx.y * (NB / NJ);        // 256 j's = 8 tiles of 32
  int lr = lane & 31;
  int hi = lane >> 5;                     // k-half selector within fragment

  // --- dual per-reg layout probe (verified R3-R6), compressed ---
  short8 pj, pc;
  unsigned short blr = f2bf((float)lr);
#pragma unroll
  for (int e = 0; e < 8; ++e) { pj[e] = (short)blr; pc[e] = (short)0x3D80; }
  f32x16 pr = {}, pn = {};
  pr = __builtin_amdgcn_mfma_f32_32x32x16_bf16(pj, pc, pr, 0, 0, 0);
  pn = __builtin_amdgcn_mfma_f32_32x32x16_bf16(pc, pj, pn, 0, 0, 0);
  unsigned int dmask = 0;   // bit r: this (lane,reg) is a tile-diagonal element
  int imv[4] = {0, 0, 0, 0};  // imap packed 4x u8 per int
#pragma unroll
  for (int r = 0; r < 16; ++r) {
    int jm = (int)(pr[r] + 0.5f), im = (int)(pn[r] + 0.5f);
    dmask |= (unsigned)(jm == im) << r;
    imv[r >> 2] |= im << ((r & 3) * 8);
  }

  // Hoist X fragments for the whole j loop: 8 contiguous bf16 = 16B load
  short8 xf[8];
#pragma unroll
  for (int ks = 0; ks < 8; ++ks)
    xf[ks] = *reinterpret_cast<const short8*>(
        Xc + ((size_t)(ks * 2 + hi) * NB + (it0 + lr)) * 8);

  float rs[16];
#pragma unroll
  for (int r = 0; r < 16; ++r) rs[r] = 0.0f;

  for (int jt = 0; jt < JTILES; ++jt) {
    int j0 = jb + jt * 32;
    short8 yf[8];
#pragma unroll
    for (int ks = 0; ks < 8; ++ks)
      yf[ks] = *reinterpret_cast<const short8*>(
          Yc + ((size_t)(ks * 2 + hi) * NB + (j0 + lr)) * 8);
    f32x16 acc = {};
#pragma unroll
    for (int ks = 0; ks < 8; ++ks)
      acc = __builtin_amdgcn_mfma_f32_32x32x16_bf16(yf[ks], xf[ks], acc, 0, 0, 0);
    // tiles are 32-aligned: diagonal intersects only when j0 == it0
    bool chk = skip && (j0 == it0);
#pragma unroll
    for (int r = 0; r < 16; ++r) {
      float e = exp2f(fmaf(acc[r], EXP_SCALE, -EXP_SCALE));
      if (chk && ((dmask >> r) & 1u)) e = 0.0f;
      rs[r] += e;
    }
  }
  // LDS reduce (2 lanes x 16 regs share each output column)
  int base = wid * 32;
#pragma unroll
  for (int r = 0; r < 16; ++r) {
    int im = (imv[r >> 2] >> ((r & 3) * 8)) & 0xFF;
    atomicAdd(&buf[base + im], rs[r]);
  }
  __syncthreads();
  if (tid < 128)
    rpart[((size_t)(z * NJ + blockIdx.y)) * NB + blockIdx.x * 128 + tid] = buf[tid];
}

__global__ __launch_bounds__(256) void k_final(
    const float* __restrict__ rpart, const float* __restrict__ diag,
    float* __restrict__ out) {
  int i = blockIdx.x * 256 + threadIdx.x;
  float sa = 0.0f, sb = 0.0f;
#pragma unroll
  for (int y = 0; y < NJ; ++y) {
    sa += rpart[(size_t)(0 * NJ + y) * NB + i] + rpart[(size_t)(1 * NJ + y) * NB + i];
    sb += rpart[(size_t)(2 * NJ + y) * NB + i] + rpart[(size_t)(3 * NJ + y) * NB + i];
  }
  // 0.5*(lse_a + lse_b) - diag ; lse = 20 + ln(sum)
  float v = 0.5f * (40.0f + logf(sa) + logf(sb)) - diag[i];
  v = wave_sum(v);
  __shared__ float sred[4];
  if ((threadIdx.x & 63) == 0) sred[threadIdx.x >> 6] = v;
  __syncthreads();
  if (threadIdx.x == 0)
    atomicAdd(out, (sred[0] + sred[1] + sred[2] + sred[3]) * (1.0f / NB));
}

extern "C" void kernel_launch(void* const* d_in, const int* in_sizes, int n_in,
                              void* d_out, int out_size, void* d_ws, size_t ws_size,
                              hipStream_t stream) {
  const float* emb = (const float*)d_in[0];
  const int* links = (const int*)d_in[1];
  char* ws = (char*)d_ws;
  float* Zi_f = (float*)(ws + 0);                        // 2 MB (dead after k_diag)
  float* Zj_f = (float*)(ws + 2097152);                  // 2 MB
  unsigned short* Zic = (unsigned short*)(ws + 4194304); // 1 MB
  unsigned short* Zjc = (unsigned short*)(ws + 5242880); // 1 MB
  float* rpart = (float*)(ws + 6291456);                 // 4*NJ*NB*4 = 1 MB
  float* diag = (float*)(ws + 7340032);                  // 16 KB
  int* flag = (int*)(ws + 7356416);                      // 4 B
  float* out = (float*)d_out;

  hipLaunchKernelGGL(k_init, dim3(1), dim3(64), 0, stream, links, flag, out);
  hipLaunchKernelGGL(k_normalize, dim3(2048), dim3(256), 0, stream,
                     emb, links, flag, Zi_f, Zj_f, Zic, Zjc);
  hipLaunchKernelGGL(k_diag, dim3(1024), dim3(256), 0, stream, Zi_f, Zj_f, diag);
  hipLaunchKernelGGL(k_pass, dim3(32, NJ, 4), dim3(256), 0, stream,
                     Zic, Zjc, rpart);
  hipLaunchKernelGGL(k_final, dim3(16), dim3(256), 0, stream,
                     rpart, diag, out);
}